// Round 3
// baseline (473.615 us; speedup 1.0000x reference)
//
#include <hip/hip_runtime.h>
#include <math.h>

#define Bq 64
#define Hq 256
#define Lq 1024
#define Nq 128
#define Gq 8
#define HSq 256
#define BHL (Bq*Hq*Lq)

typedef __bf16 bf16_t;
typedef __bf16 bf16x8 __attribute__((ext_vector_type(8)));
typedef float f32x4 __attribute__((ext_vector_type(4)));

union U2 { uint2 u; bf16_t e[4]; };
union F4 { float4 v; float e[4]; };

// ---------------- GroupNorm stats: one block per (b,g) --------------------
__global__ __launch_bounds__(256) void k_stats(const float* __restrict__ x,
                                               float* __restrict__ stats) {
    int bg = blockIdx.x;
    const float* xp = x + (size_t)bg * (32 * Lq);
    float s1 = 0.f, s2 = 0.f;
    for (int i = threadIdx.x; i < 32 * Lq / 4; i += 256) {
        float4 v = ((const float4*)xp)[i];
        s1 += v.x + v.y + v.z + v.w;
        s2 += v.x*v.x + v.y*v.y + v.z*v.z + v.w*v.w;
    }
    __shared__ float r1[256], r2[256];
    r1[threadIdx.x] = s1; r2[threadIdx.x] = s2;
    __syncthreads();
    for (int s = 128; s > 0; s >>= 1) {
        if (threadIdx.x < s) { r1[threadIdx.x] += r1[threadIdx.x+s];
                               r2[threadIdx.x] += r2[threadIdx.x+s]; }
        __syncthreads();
    }
    if (threadIdx.x == 0) {
        const float inv = 1.f / (32.f * Lq);
        float mu  = r1[0] * inv;
        float var = r2[0] * inv - mu * mu;
        stats[bg*2]   = mu;
        stats[bg*2+1] = rsqrtf(var + 1e-5f);
    }
}

// ---------------- diffusion projection d[b,o] -----------------------------
__global__ __launch_bounds__(256) void k_dproj(const float* __restrict__ emb,
                                               const float* __restrict__ dw,
                                               const float* __restrict__ db,
                                               float* __restrict__ d) {
    int i = blockIdx.x * 256 + threadIdx.x;
    int b = i >> 8, o = i & 255;
    const float* e = emb + b * 256;
    const float* w = dw + o * 256;
    float acc = 0.f;
    for (int k = 0; k < 256; k += 4) {
        float4 ev = *(const float4*)(e + k);
        float4 wv = *(const float4*)(w + k);
        acc += ev.x*wv.x + ev.y*wv.y + ev.z*wv.z + ev.w*wv.w;
    }
    d[i] = acc + db[o];
}

// ------- fused u = gn(x)*w + b + d (bf16) -> ub AND ubT (LDS transpose) ---
// grid: b(64) x h-tile(4) x l-tile(16); 64x64 tile per block.
__global__ __launch_bounds__(256) void k_unt(const float* __restrict__ x,
                                             const float* __restrict__ stats,
                                             const float* __restrict__ gnw,
                                             const float* __restrict__ gnb,
                                             const float* __restrict__ d,
                                             bf16_t* __restrict__ ub,
                                             bf16_t* __restrict__ ubT) {
    int b  = blockIdx.x >> 6;
    int r0 = ((blockIdx.x >> 4) & 3) << 6;
    int c0 = (blockIdx.x & 15) << 6;
    __shared__ __align__(16) bf16_t t[64][72];   // 144B rows (9x16B)
    int tid = threadIdx.x;
    int r = tid >> 2, cs = (tid & 3) * 16;
    int c = r0 + r;                              // channel
    int g = c >> 5;
    float mu = stats[(b*Gq+g)*2], rs = stats[(b*Gq+g)*2+1];
    float sc = rs * gnw[c];
    float sh = gnb[c] + d[b*Hq + c] - mu * sc;
    const float* sp = x + ((size_t)b*Hq + c)*Lq + c0 + cs;
    float4 f0 = *(const float4*)sp;
    float4 f1 = *(const float4*)(sp + 4);
    float4 f2 = *(const float4*)(sp + 8);
    float4 f3 = *(const float4*)(sp + 12);
    union { uint4 u; bf16_t e[8]; } v0, v1;
    v0.e[0]=(bf16_t)(f0.x*sc+sh); v0.e[1]=(bf16_t)(f0.y*sc+sh);
    v0.e[2]=(bf16_t)(f0.z*sc+sh); v0.e[3]=(bf16_t)(f0.w*sc+sh);
    v0.e[4]=(bf16_t)(f1.x*sc+sh); v0.e[5]=(bf16_t)(f1.y*sc+sh);
    v0.e[6]=(bf16_t)(f1.z*sc+sh); v0.e[7]=(bf16_t)(f1.w*sc+sh);
    v1.e[0]=(bf16_t)(f2.x*sc+sh); v1.e[1]=(bf16_t)(f2.y*sc+sh);
    v1.e[2]=(bf16_t)(f2.z*sc+sh); v1.e[3]=(bf16_t)(f2.w*sc+sh);
    v1.e[4]=(bf16_t)(f3.x*sc+sh); v1.e[5]=(bf16_t)(f3.y*sc+sh);
    v1.e[6]=(bf16_t)(f3.z*sc+sh); v1.e[7]=(bf16_t)(f3.w*sc+sh);
    bf16_t* up = ub + ((size_t)b*Hq + c)*Lq + c0 + cs;
    *(uint4*)up       = v0.u;
    *(uint4*)(up + 8) = v1.u;
#pragma unroll
    for (int j = 0; j < 8; j++) { t[cs + j][r] = v0.e[j]; t[cs + 8 + j][r] = v1.e[j]; }
    __syncthreads();
    bf16_t* dp = ubT + ((size_t)b*Lq + c0 + r)*Hq + r0 + (tid & 3)*16;
    *(uint4*)dp       = *(const uint4*)&t[r][(tid & 3)*16];
    *(uint4*)(dp + 8) = *(const uint4*)&t[r][(tid & 3)*16 + 8];
}

// ---------------- transpose [B][256][1024] -> [B][1024][256] (bf16) -------
__global__ __launch_bounds__(256) void k_tr(const bf16_t* __restrict__ src,
                                            bf16_t* __restrict__ dst) {
    int b  = blockIdx.x >> 6;
    int r0 = ((blockIdx.x >> 4) & 3) << 6;
    int c0 = (blockIdx.x & 15) << 6;
    __shared__ __align__(16) bf16_t t[64][72];   // 144B rows (9x16B)
    int tid = threadIdx.x;
    int r = tid >> 2, cs = (tid & 3) * 16;
    const bf16_t* sp = src + ((size_t)b*256 + r0 + r)*1024 + c0 + cs;
    union { uint4 u; bf16_t e[8]; } v0, v1;
    v0.u = *(const uint4*)sp;
    v1.u = *(const uint4*)(sp + 8);
#pragma unroll
    for (int j = 0; j < 8; j++) { t[cs + j][r] = v0.e[j]; t[cs + 8 + j][r] = v1.e[j]; }
    __syncthreads();
    bf16_t* dp = dst + ((size_t)b*1024 + c0 + r)*256 + r0 + (tid & 3)*16;
    *(uint4*)dp       = *(const uint4*)&t[r][(tid & 3)*16];
    *(uint4*)(dp + 8) = *(const uint4*)&t[r][(tid & 3)*16 + 8];
}

// ---------------- weights fp32 -> bf16 ------------------------------------
__global__ __launch_bounds__(256) void k_wcvt(const float* __restrict__ ow,
                                              const float* __restrict__ rw,
                                              const float* __restrict__ sw,
                                              bf16_t* __restrict__ owb,
                                              bf16_t* __restrict__ rsb) {
    int i = blockIdx.x * 256 + threadIdx.x;      // [0, 131072)
    owb[i] = (bf16_t)ow[i];
    rsb[i] = (bf16_t)((i < 65536) ? rw[i] : sw[i - 65536]);
}

// ---------------- S4D kernel -> reversed padded bf16 Krev -----------------
// Krev[h][j] = (256 <= j <= 1279) ? K[h][1279 - j] : 0 ;  row size 1536
// Table method: exp(dtA*l) = W-table[j] * eb-table[i], l = 32j + i.
__global__ __launch_bounds__(256) void k_kern(const float* __restrict__ log_dt,
                                              const float* __restrict__ Are,
                                              const float* __restrict__ Aim,
                                              const float* __restrict__ Cre,
                                              const float* __restrict__ Cim,
                                              bf16_t* __restrict__ Krev) {
    int h = blockIdx.x;
    __shared__ __align__(16) float2 Wt[32][130];   // W[j][n] = Ct_n * exp(dtA_n*32j)
    __shared__ __align__(16) float2 ebt[128][34];  // eb[n][i] = exp(dtA_n*i)
    int tid = threadIdx.x;
    bf16_t* Kh = Krev + (size_t)h * 1536;
    Kh[tid]        = (bf16_t)0.f;
    Kh[1280 + tid] = (bf16_t)0.f;
    if (tid < Nq) {
        int n = tid;
        float dt = expf(log_dt[h]);
        float ar = Are[h*Nq+n], ai = Aim[h*Nq+n];
        float a = dt * ar, bb = dt * ai;
        float e = expf(a);
        float s1, c1; sincosf(bb, &s1, &c1);
        float wr = e * c1, wi = e * s1;            // w = exp(dtA)
        float er = wr - 1.f, ei = wi;
        float den = ar*ar + ai*ai;
        float dr = (er*ar + ei*ai) / den;
        float di = (ei*ar - er*ai) / den;
        float cr = Cre[h*Nq+n], ci = Cim[h*Nq+n];
        float ctr = cr*dr - ci*di;
        float cti = cr*di + ci*dr;
        float zr = 1.f, zi = 0.f;
#pragma unroll 4
        for (int i = 0; i < 32; ++i) {
            ebt[n][i] = make_float2(zr, zi);
            float tr_ = zr*wr - zi*wi;
            zi = zr*wi + zi*wr; zr = tr_;
        }
        float e32 = expf(32.f * a);
        float s32, c32; sincosf(32.f * bb, &s32, &c32);
        float w32r = e32 * c32, w32i = e32 * s32;
        float ur = ctr, ui = cti;                  // W[0] = Ct
#pragma unroll 4
        for (int j = 0; j < 32; ++j) {
            Wt[j][n] = make_float2(ur, ui);
            float tr_ = ur*w32r - ui*w32i;
            ui = ur*w32i + ui*w32r; ur = tr_;
        }
    }
    __syncthreads();
    int j = tid >> 3, i0 = (tid & 7) * 4;
    float acc0 = 0.f, acc1 = 0.f, acc2 = 0.f, acc3 = 0.f;
#pragma unroll 4
    for (int n = 0; n < Nq; ++n) {
        float2 w = Wt[j][n];
        float4 e01 = *(const float4*)&ebt[n][i0];
        float4 e23 = *(const float4*)&ebt[n][i0 + 2];
        acc0 += w.x*e01.x - w.y*e01.y;
        acc1 += w.x*e01.z - w.y*e01.w;
        acc2 += w.x*e23.x - w.y*e23.y;
        acc3 += w.x*e23.z - w.y*e23.w;
    }
    int l = j*32 + i0;
    Kh[1279 - l]     = (bf16_t)(2.f * acc0);
    Kh[1279 - l - 1] = (bf16_t)(2.f * acc1);
    Kh[1279 - l - 2] = (bf16_t)(2.f * acc2);
    Kh[1279 - l - 3] = (bf16_t)(2.f * acc3);
}

// ---- replica row builder: shK[s][i] = Krev[i + 7 - s], via static funnel shift
template<int SH>
__device__ __forceinline__ void build_row(bf16_t* __restrict__ dst,
                                          const uint4* __restrict__ kb,
                                          int ln) {
#pragma unroll
    for (int r = 0; r < 3; ++r) {
        int c = ln + r * 64;                     // 192 chunks of 16B per row
        uint4 lo = kb[c];
        uint4 hi = kb[c + 1];
        unsigned int wd[8] = {lo.x, lo.y, lo.z, lo.w, hi.x, hi.y, hi.z, hi.w};
        uint4 o;
        constexpr int J = SH >> 2;
        if constexpr ((SH & 2) != 0) {
            o.x = (unsigned int)((((unsigned long long)wd[J+1] << 32) | wd[J+0]) >> 16);
            o.y = (unsigned int)((((unsigned long long)wd[J+2] << 32) | wd[J+1]) >> 16);
            o.z = (unsigned int)((((unsigned long long)wd[J+3] << 32) | wd[J+2]) >> 16);
            o.w = (unsigned int)((((unsigned long long)wd[J+4] << 32) | wd[J+3]) >> 16);
        } else {
            o.x = wd[J+0]; o.y = wd[J+1]; o.z = wd[J+2]; o.w = wd[J+3];
        }
        *(uint4*)(dst + c * 8) = o;
    }
}

// ---------------- causal conv (Toeplitz MFMA) + D*u + gelu -> gy bf16 -----
__global__ __launch_bounds__(512, 2) void k_conv(const bf16_t* __restrict__ ub,
                                                 const bf16_t* __restrict__ Krev,
                                                 const float* __restrict__ Dp,
                                                 bf16_t* __restrict__ gy) {
    int h = blockIdx.x;
    __shared__ __align__(16) bf16_t shK[8][1560];   // 24960 B
    __shared__ __align__(16) bf16_t ut[2][64][72];  // 18432 B
    int tid = threadIdx.x, lane = tid & 63, wv = tid >> 6;
    int q = lane >> 4, ln = lane & 15;

    const bf16_t* Kg = Krev + (size_t)h * 1536;
    {
        bf16_t* kb = &ut[0][0][0];
        if (tid < 192) *(uint4*)&kb[tid * 8] = *(const uint4*)&Kg[tid * 8];
        __syncthreads();
        const uint4* kb4 = (const uint4*)kb;
        bf16_t* dst = &shK[wv][0];
        switch (wv) {
            case 0: build_row<14>(dst, kb4, lane); break;
            case 1: build_row<12>(dst, kb4, lane); break;
            case 2: build_row<10>(dst, kb4, lane); break;
            case 3: build_row< 8>(dst, kb4, lane); break;
            case 4: build_row< 6>(dst, kb4, lane); break;
            case 5: build_row< 4>(dst, kb4, lane); break;
            case 6: build_row< 2>(dst, kb4, lane); break;
            default: build_row< 0>(dst, kb4, lane); break;
        }
        __syncthreads();
    }

    int sb = tid >> 3, sseg = tid & 7;
    const bf16_t* usrc = ub + ((size_t)sb * Hq + h) * Lq + sseg * 8;
    *(uint4*)&ut[0][sb][sseg * 8] = *(const uint4*)usrc;   // prologue t0=0

    f32x4 acc[8][4];
#pragma unroll
    for (int i = 0; i < 8; ++i)
#pragma unroll
        for (int j = 0; j < 4; ++j) acc[i][j] = (f32x4){0.f, 0.f, 0.f, 0.f};

    int Wl = wv << 7;
    float Dh = Dp[h];
    int cbase = 1279 - Wl + q * 8 - 7 - ((ln >> 3) << 3);
    const bf16_t* arow = &shK[ln & 7][0];
    __syncthreads();

#pragma unroll 2
    for (int step = 0; step < 16; ++step) {
        int t0 = step << 6;
        int cur = step & 1;
        uint4 pre;
        if (step < 15) pre = *(const uint4*)(usrc + t0 + 64);
        if (t0 < Wl + 128) {
            bf16x8 bfr[4][2];
#pragma unroll
            for (int nf = 0; nf < 4; ++nf)
#pragma unroll
                for (int kk = 0; kk < 2; ++kk)
                    bfr[nf][kk] = *(const bf16x8*)&ut[cur][nf * 16 + ln][kk * 32 + q * 8];
#pragma unroll
            for (int mf = 0; mf < 8; ++mf) {
#pragma unroll
                for (int kk = 0; kk < 2; ++kk) {
                    bf16x8 af = *(const bf16x8*)&arow[cbase + t0 + kk * 32 - mf * 16];
#pragma unroll
                    for (int nf = 0; nf < 4; ++nf)
                        acc[mf][nf] = __builtin_amdgcn_mfma_f32_16x16x32_bf16(
                            af, bfr[nf][kk], acc[mf][nf], 0, 0, 0);
                }
            }
            int ph = step - (wv << 1);
            if (ph == 0 || ph == 1) {
#pragma unroll
                for (int mh = 0; mh < 4; ++mh)
#pragma unroll
                    for (int nf = 0; nf < 4; ++nf) {
                        U2 uv;
                        uv.u = *(const uint2*)&ut[cur][nf * 16 + ln][mh * 16 + q * 4];
                        if (ph == 0) {
#pragma unroll
                            for (int rr = 0; rr < 4; ++rr)
                                acc[mh][nf][rr] += Dh * (float)uv.e[rr];
                        } else {
#pragma unroll
                            for (int rr = 0; rr < 4; ++rr)
                                acc[mh + 4][nf][rr] += Dh * (float)uv.e[rr];
                        }
                    }
            }
        }
        if (step < 15) *(uint4*)&ut[cur ^ 1][sb][sseg * 8] = pre;
        __syncthreads();
    }

#pragma unroll
    for (int mf = 0; mf < 8; ++mf) {
        int l = Wl + mf * 16 + q * 4;
#pragma unroll
        for (int nf = 0; nf < 4; ++nf) {
            int bb = nf * 16 + ln;
            size_t off = ((size_t)bb * Hq + h) * Lq + l;
            U2 ov;
#pragma unroll
            for (int rr = 0; rr < 4; ++rr) {
                float y = acc[mf][nf][rr];
                float t = 0.7978845608028654f * (y + 0.044715f * y * y * y);
                ov.e[rr] = (bf16_t)(0.5f * y * (1.f + tanhf(t)));
            }
            *(uint2*)&gy[off] = ov.u;
        }
    }
}

// ------- fused projA+projB: K-resident, no inner barriers -----------------
// One block per (b, l-128-tile); 512 threads (8 waves); LDS tile 128x264.
// Phase 1: stage gy tile [128 l][256 k].  GEMM1: v = owb@gy (weights from L2).
// Phase 2: overwrite tile with u; GLU in place -> h2 tile.
// Phase 3: GEMM2: res/skip = rsb@h2 (h2 from LDS A-frags, rsb from L2).
#define TBS 264
__global__ __launch_bounds__(512, 2) void k_projAB(const bf16_t* __restrict__ gyT,
                                                   const bf16_t* __restrict__ owb,
                                                   const float* __restrict__ ob,
                                                   const bf16_t* __restrict__ ubT,
                                                   const bf16_t* __restrict__ rsb,
                                                   const float* __restrict__ rb,
                                                   const float* __restrict__ sb,
                                                   const float* __restrict__ x,
                                                   float* __restrict__ out) {
    int bid = blockIdx.x;
    int b  = bid >> 3;
    int l0 = (bid & 7) << 7;
    __shared__ __align__(16) bf16_t TB[128 * TBS];   // 67584 B
    int tid = threadIdx.x, lane = tid & 63, wv = tid >> 6;
    int q = lane >> 4, ln = lane & 15;
    int lh = wv & 1, og = wv >> 1;        // l-half (64), o-group

    // ---- stage gy tile: TB[r][k] = gyT[b][l0+r][k]
    int sr = tid >> 2, sc = (tid & 3) * 8;          // 4 threads/row, 8 cols apart
    {
        const bf16_t* gsrc = gyT + ((size_t)b * Lq + l0 + sr) * 256 + sc;
        bf16_t* grow = &TB[sr * TBS + sc];
#pragma unroll
        for (int i = 0; i < 8; ++i)
            *(uint4*)(grow + i * 32) = *(const uint4*)(gsrc + i * 32);
    }
    __syncthreads();

    // ---- GEMM1: acc[mf][nf]; mf 0-3 = v1 rows og*64+mf*16, mf 4-7 = v2 (+256)
    f32x4 acc[8][4];
#pragma unroll
    for (int i = 0; i < 8; ++i)
#pragma unroll
        for (int j = 0; j < 4; ++j) acc[i][j] = (f32x4){0.f, 0.f, 0.f, 0.f};

#pragma unroll
    for (int kk = 0; kk < 8; ++kk) {
        bf16x8 bfr[4];
#pragma unroll
        for (int nf = 0; nf < 4; ++nf)
            bfr[nf] = *(const bf16x8*)&TB[(lh * 64 + nf * 16 + ln) * TBS + kk * 32 + q * 8];
#pragma unroll
        for (int mf = 0; mf < 8; ++mf) {
            int orow = (mf < 4) ? (og * 64 + mf * 16 + ln)
                                : (256 + og * 64 + (mf - 4) * 16 + ln);
            bf16x8 af = *(const bf16x8*)&owb[(size_t)orow * 256 + kk * 32 + q * 8];
#pragma unroll
            for (int nf = 0; nf < 4; ++nf)
                acc[mf][nf] = __builtin_amdgcn_mfma_f32_16x16x32_bf16(
                    af, bfr[nf], acc[mf][nf], 0, 0, 0);
        }
    }
    __syncthreads();

    // ---- stage u tile over TB: TB[r][c] = ubT[b][l0+r][c]
    {
        const bf16_t* usrc = ubT + ((size_t)b * Lq + l0 + sr) * 256 + sc;
        bf16_t* urow = &TB[sr * TBS + sc];
#pragma unroll
        for (int i = 0; i < 8; ++i)
            *(uint4*)(urow + i * 32) = *(const uint4*)(usrc + i * 32);
    }
    __syncthreads();

    // ---- GLU + u-add, in place: TB[row][c] = v1*sig(v2) + u
#pragma unroll
    for (int mf = 0; mf < 4; ++mf) {
        int c = og * 64 + mf * 16 + q * 4;
        F4 b1, b2;
        b1.v = *(const float4*)&ob[c];
        b2.v = *(const float4*)&ob[c + 256];
#pragma unroll
        for (int nf = 0; nf < 4; ++nf) {
            int row = lh * 64 + nf * 16 + ln;
            bf16_t* tp = &TB[row * TBS + c];
            U2 uv; uv.u = *(const uint2*)tp;
            U2 hv;
#pragma unroll
            for (int rr = 0; rr < 4; ++rr) {
                float v1 = acc[mf][nf][rr]     + b1.e[rr];
                float v2 = acc[mf + 4][nf][rr] + b2.e[rr];
                float sg = 1.f / (1.f + expf(-v2));
                hv.e[rr] = (bf16_t)(v1 * sg + (float)uv.e[rr]);
            }
            *(uint2*)tp = hv.u;
        }
    }
    __syncthreads();

    // ---- GEMM2: acc2[mf l][nf o2]; A = h2 from LDS rows l, B = rsb rows o2
    f32x4 acc2[4][8];
#pragma unroll
    for (int i = 0; i < 4; ++i)
#pragma unroll
        for (int j = 0; j < 8; ++j) acc2[i][j] = (f32x4){0.f, 0.f, 0.f, 0.f};

#pragma unroll
    for (int kk = 0; kk < 8; ++kk) {
        bf16x8 afr[4];
#pragma unroll
        for (int mf = 0; mf < 4; ++mf)
            afr[mf] = *(const bf16x8*)&TB[(lh * 64 + mf * 16 + ln) * TBS + kk * 32 + q * 8];
#pragma unroll
        for (int nf = 0; nf < 8; ++nf) {
            int o2 = og * 128 + nf * 16 + ln;
            bf16x8 bf_ = *(const bf16x8*)&rsb[(size_t)o2 * 256 + kk * 32 + q * 8];
#pragma unroll
            for (int mf = 0; mf < 4; ++mf)
                acc2[mf][nf] = __builtin_amdgcn_mfma_f32_16x16x32_bf16(
                    afr[mf], bf_, acc2[mf][nf], 0, 0, 0);
        }
    }

    // ---- epilogue: res (o2<256) += x, scale; skip (o2>=256) + sb
#pragma unroll
    for (int nf = 0; nf < 8; ++nf) {
        int o2 = og * 128 + nf * 16 + ln;
#pragma unroll
        for (int mf = 0; mf < 4; ++mf) {
            int l = l0 + lh * 64 + mf * 16 + q * 4;
            if (o2 < 256) {
                F4 xv; xv.v = *(const float4*)&x[((size_t)b * Hq + o2) * Lq + l];
                float rbv = rb[o2];
                F4 ov;
#pragma unroll
                for (int rr = 0; rr < 4; ++rr)
                    ov.e[rr] = (acc2[mf][nf][rr] + rbv + xv.e[rr]) * 0.70710678118654752f;
                *(float4*)&out[((size_t)b * Hq + o2) * Lq + l] = ov.v;
            } else {
                int c = o2 - 256;
                float sbv = sb[c];
                F4 ov;
#pragma unroll
                for (int rr = 0; rr < 4; ++rr)
                    ov.e[rr] = acc2[mf][nf][rr] + sbv;
                *(float4*)&out[(size_t)BHL + ((size_t)b * HSq + c) * Lq + l] = ov.v;
            }
        }
    }
}

extern "C" void kernel_launch(void* const* d_in, const int* in_sizes, int n_in,
                              void* d_out, int out_size, void* d_ws, size_t ws_size,
                              hipStream_t stream) {
    const float* x      = (const float*)d_in[0];
    const float* emb    = (const float*)d_in[1];
    const float* gnw    = (const float*)d_in[2];
    const float* gnb    = (const float*)d_in[3];
    const float* dpw    = (const float*)d_in[4];
    const float* dpb    = (const float*)d_in[5];
    const float* log_dt = (const float*)d_in[6];
    const float* Are    = (const float*)d_in[7];
    const float* Aim    = (const float*)d_in[8];
    const float* Cre    = (const float*)d_in[9];
    const float* Cim    = (const float*)d_in[10];
    const float* Dp     = (const float*)d_in[11];
    const float* ow     = (const float*)d_in[12];
    const float* ob     = (const float*)d_in[13];
    const float* rw     = (const float*)d_in[14];
    const float* rb     = (const float*)d_in[15];
    const float* sw     = (const float*)d_in[16];
    const float* sb     = (const float*)d_in[17];
    float* out = (float*)d_out;

    bf16_t* ub   = (bf16_t*)d_ws;                    // [B][H][L] bf16
    bf16_t* ubT  = ub   + (size_t)BHL;               // [B][L][H] bf16
    bf16_t* gy   = ubT  + (size_t)BHL;               // [B][H][L] bf16
    bf16_t* Krev = gy   + (size_t)BHL;               // [H][1536] bf16
    bf16_t* owb  = Krev + (size_t)256*1536;          // [512][256] bf16
    bf16_t* rsb  = owb  + (size_t)512*256;           // [512][256] bf16
    float*  dprj = (float*)(rsb + (size_t)512*256);  // [B][H]
    float*  stats = dprj + (size_t)Bq*Hq;            // [B*G][2]
    bf16_t* gyT = ub;    // reuse: ub dead after k_conv

    k_stats<<<Bq*Gq, 256, 0, stream>>>(x, stats);
    k_dproj<<<Bq*Hq/256, 256, 0, stream>>>(emb, dpw, dpb, dprj);
    k_unt<<<Bq*64, 256, 0, stream>>>(x, stats, gnw, gnb, dprj, ub, ubT);
    k_wcvt<<<512, 256, 0, stream>>>(ow, rw, sw, owb, rsb);
    k_kern<<<Hq, 256, 0, stream>>>(log_dt, Are, Aim, Cre, Cim, Krev);
    k_conv<<<Hq, 512, 0, stream>>>(ub, Krev, Dp, gy);
    k_tr<<<Bq*64, 256, 0, stream>>>(gy, gyT);
    k_projAB<<<Bq*8, 512, 0, stream>>>(gyT, owb, ob, ubT, rsb, rb, sb, x, out);
}

// Round 4
// 456.141 us; speedup vs baseline: 1.0383x; 1.0383x over previous
//
#include <hip/hip_runtime.h>
#include <math.h>

#define Bq 64
#define Hq 256
#define Lq 1024
#define Nq 128
#define Gq 8
#define HSq 256
#define BHL (Bq*Hq*Lq)

typedef __bf16 bf16_t;
typedef __bf16 bf16x8 __attribute__((ext_vector_type(8)));
typedef float f32x4 __attribute__((ext_vector_type(4)));

union U2 { uint2 u; bf16_t e[4]; };
union F4 { float4 v; float e[4]; };

// ---------------- GroupNorm stats: one block per (b,g) --------------------
__global__ __launch_bounds__(256) void k_stats(const float* __restrict__ x,
                                               float* __restrict__ stats) {
    int bg = blockIdx.x;
    const float* xp = x + (size_t)bg * (32 * Lq);
    float s1 = 0.f, s2 = 0.f;
    for (int i = threadIdx.x; i < 32 * Lq / 4; i += 256) {
        float4 v = ((const float4*)xp)[i];
        s1 += v.x + v.y + v.z + v.w;
        s2 += v.x*v.x + v.y*v.y + v.z*v.z + v.w*v.w;
    }
    __shared__ float r1[256], r2[256];
    r1[threadIdx.x] = s1; r2[threadIdx.x] = s2;
    __syncthreads();
    for (int s = 128; s > 0; s >>= 1) {
        if (threadIdx.x < s) { r1[threadIdx.x] += r1[threadIdx.x+s];
                               r2[threadIdx.x] += r2[threadIdx.x+s]; }
        __syncthreads();
    }
    if (threadIdx.x == 0) {
        const float inv = 1.f / (32.f * Lq);
        float mu  = r1[0] * inv;
        float var = r2[0] * inv - mu * mu;
        stats[bg*2]   = mu;
        stats[bg*2+1] = rsqrtf(var + 1e-5f);
    }
}

// ---------------- diffusion projection d[b,o] -----------------------------
__global__ __launch_bounds__(256) void k_dproj(const float* __restrict__ emb,
                                               const float* __restrict__ dw,
                                               const float* __restrict__ db,
                                               float* __restrict__ d) {
    int i = blockIdx.x * 256 + threadIdx.x;
    int b = i >> 8, o = i & 255;
    const float* e = emb + b * 256;
    const float* w = dw + o * 256;
    float acc = 0.f;
    for (int k = 0; k < 256; k += 4) {
        float4 ev = *(const float4*)(e + k);
        float4 wv = *(const float4*)(w + k);
        acc += ev.x*wv.x + ev.y*wv.y + ev.z*wv.z + ev.w*wv.w;
    }
    d[i] = acc + db[o];
}

// ------- fused u = gn(x)*w + b + d (bf16) -> ub AND ubT (LDS transpose) ---
// grid: b(64) x h-tile(4) x l-tile(16); 64x64 tile per block.
__global__ __launch_bounds__(256) void k_unt(const float* __restrict__ x,
                                             const float* __restrict__ stats,
                                             const float* __restrict__ gnw,
                                             const float* __restrict__ gnb,
                                             const float* __restrict__ d,
                                             bf16_t* __restrict__ ub,
                                             bf16_t* __restrict__ ubT) {
    int b  = blockIdx.x >> 6;
    int r0 = ((blockIdx.x >> 4) & 3) << 6;
    int c0 = (blockIdx.x & 15) << 6;
    __shared__ __align__(16) bf16_t t[64][72];   // 144B rows (9x16B)
    int tid = threadIdx.x;
    int r = tid >> 2, cs = (tid & 3) * 16;
    int c = r0 + r;                              // channel
    int g = c >> 5;
    float mu = stats[(b*Gq+g)*2], rs = stats[(b*Gq+g)*2+1];
    float sc = rs * gnw[c];
    float sh = gnb[c] + d[b*Hq + c] - mu * sc;
    const float* sp = x + ((size_t)b*Hq + c)*Lq + c0 + cs;
    float4 f0 = *(const float4*)sp;
    float4 f1 = *(const float4*)(sp + 4);
    float4 f2 = *(const float4*)(sp + 8);
    float4 f3 = *(const float4*)(sp + 12);
    union { uint4 u; bf16_t e[8]; } v0, v1;
    v0.e[0]=(bf16_t)(f0.x*sc+sh); v0.e[1]=(bf16_t)(f0.y*sc+sh);
    v0.e[2]=(bf16_t)(f0.z*sc+sh); v0.e[3]=(bf16_t)(f0.w*sc+sh);
    v0.e[4]=(bf16_t)(f1.x*sc+sh); v0.e[5]=(bf16_t)(f1.y*sc+sh);
    v0.e[6]=(bf16_t)(f1.z*sc+sh); v0.e[7]=(bf16_t)(f1.w*sc+sh);
    v1.e[0]=(bf16_t)(f2.x*sc+sh); v1.e[1]=(bf16_t)(f2.y*sc+sh);
    v1.e[2]=(bf16_t)(f2.z*sc+sh); v1.e[3]=(bf16_t)(f2.w*sc+sh);
    v1.e[4]=(bf16_t)(f3.x*sc+sh); v1.e[5]=(bf16_t)(f3.y*sc+sh);
    v1.e[6]=(bf16_t)(f3.z*sc+sh); v1.e[7]=(bf16_t)(f3.w*sc+sh);
    bf16_t* up = ub + ((size_t)b*Hq + c)*Lq + c0 + cs;
    *(uint4*)up       = v0.u;
    *(uint4*)(up + 8) = v1.u;
#pragma unroll
    for (int j = 0; j < 8; j++) { t[cs + j][r] = v0.e[j]; t[cs + 8 + j][r] = v1.e[j]; }
    __syncthreads();
    bf16_t* dp = ubT + ((size_t)b*Lq + c0 + r)*Hq + r0 + (tid & 3)*16;
    *(uint4*)dp       = *(const uint4*)&t[r][(tid & 3)*16];
    *(uint4*)(dp + 8) = *(const uint4*)&t[r][(tid & 3)*16 + 8];
}

// ---------------- transpose [B][256][1024] -> [B][1024][256] (bf16) -------
__global__ __launch_bounds__(256) void k_tr(const bf16_t* __restrict__ src,
                                            bf16_t* __restrict__ dst) {
    int b  = blockIdx.x >> 6;
    int r0 = ((blockIdx.x >> 4) & 3) << 6;
    int c0 = (blockIdx.x & 15) << 6;
    __shared__ __align__(16) bf16_t t[64][72];   // 144B rows (9x16B)
    int tid = threadIdx.x;
    int r = tid >> 2, cs = (tid & 3) * 16;
    const bf16_t* sp = src + ((size_t)b*256 + r0 + r)*1024 + c0 + cs;
    union { uint4 u; bf16_t e[8]; } v0, v1;
    v0.u = *(const uint4*)sp;
    v1.u = *(const uint4*)(sp + 8);
#pragma unroll
    for (int j = 0; j < 8; j++) { t[cs + j][r] = v0.e[j]; t[cs + 8 + j][r] = v1.e[j]; }
    __syncthreads();
    bf16_t* dp = dst + ((size_t)b*1024 + c0 + r)*256 + r0 + (tid & 3)*16;
    *(uint4*)dp       = *(const uint4*)&t[r][(tid & 3)*16];
    *(uint4*)(dp + 8) = *(const uint4*)&t[r][(tid & 3)*16 + 8];
}

// ---------------- weights fp32 -> bf16 ------------------------------------
__global__ __launch_bounds__(256) void k_wcvt(const float* __restrict__ ow,
                                              const float* __restrict__ rw,
                                              const float* __restrict__ sw,
                                              bf16_t* __restrict__ owb,
                                              bf16_t* __restrict__ rsb) {
    int i = blockIdx.x * 256 + threadIdx.x;      // [0, 131072)
    owb[i] = (bf16_t)ow[i];
    rsb[i] = (bf16_t)((i < 65536) ? rw[i] : sw[i - 65536]);
}

// ---------------- S4D kernel -> reversed padded bf16 Krev -----------------
// Krev[h][j] = (256 <= j <= 1279) ? K[h][1279 - j] : 0 ;  row size 1536
// Table method: exp(dtA*l) = W-table[j] * eb-table[i], l = 32j + i.
__global__ __launch_bounds__(256) void k_kern(const float* __restrict__ log_dt,
                                              const float* __restrict__ Are,
                                              const float* __restrict__ Aim,
                                              const float* __restrict__ Cre,
                                              const float* __restrict__ Cim,
                                              bf16_t* __restrict__ Krev) {
    int h = blockIdx.x;
    __shared__ __align__(16) float2 Wt[32][130];   // W[j][n] = Ct_n * exp(dtA_n*32j)
    __shared__ __align__(16) float2 ebt[128][34];  // eb[n][i] = exp(dtA_n*i)
    int tid = threadIdx.x;
    bf16_t* Kh = Krev + (size_t)h * 1536;
    Kh[tid]        = (bf16_t)0.f;
    Kh[1280 + tid] = (bf16_t)0.f;
    if (tid < Nq) {
        int n = tid;
        float dt = expf(log_dt[h]);
        float ar = Are[h*Nq+n], ai = Aim[h*Nq+n];
        float a = dt * ar, bb = dt * ai;
        float e = expf(a);
        float s1, c1; sincosf(bb, &s1, &c1);
        float wr = e * c1, wi = e * s1;            // w = exp(dtA)
        float er = wr - 1.f, ei = wi;
        float den = ar*ar + ai*ai;
        float dr = (er*ar + ei*ai) / den;
        float di = (ei*ar - er*ai) / den;
        float cr = Cre[h*Nq+n], ci = Cim[h*Nq+n];
        float ctr = cr*dr - ci*di;
        float cti = cr*di + ci*dr;
        float zr = 1.f, zi = 0.f;
#pragma unroll 4
        for (int i = 0; i < 32; ++i) {
            ebt[n][i] = make_float2(zr, zi);
            float tr_ = zr*wr - zi*wi;
            zi = zr*wi + zi*wr; zr = tr_;
        }
        float e32 = expf(32.f * a);
        float s32, c32; sincosf(32.f * bb, &s32, &c32);
        float w32r = e32 * c32, w32i = e32 * s32;
        float ur = ctr, ui = cti;                  // W[0] = Ct
#pragma unroll 4
        for (int j = 0; j < 32; ++j) {
            Wt[j][n] = make_float2(ur, ui);
            float tr_ = ur*w32r - ui*w32i;
            ui = ur*w32i + ui*w32r; ur = tr_;
        }
    }
    __syncthreads();
    int j = tid >> 3, i0 = (tid & 7) * 4;
    float acc0 = 0.f, acc1 = 0.f, acc2 = 0.f, acc3 = 0.f;
#pragma unroll 4
    for (int n = 0; n < Nq; ++n) {
        float2 w = Wt[j][n];
        float4 e01 = *(const float4*)&ebt[n][i0];
        float4 e23 = *(const float4*)&ebt[n][i0 + 2];
        acc0 += w.x*e01.x - w.y*e01.y;
        acc1 += w.x*e01.z - w.y*e01.w;
        acc2 += w.x*e23.x - w.y*e23.y;
        acc3 += w.x*e23.z - w.y*e23.w;
    }
    int l = j*32 + i0;
    Kh[1279 - l]     = (bf16_t)(2.f * acc0);
    Kh[1279 - l - 1] = (bf16_t)(2.f * acc1);
    Kh[1279 - l - 2] = (bf16_t)(2.f * acc2);
    Kh[1279 - l - 3] = (bf16_t)(2.f * acc3);
}

// ---- replica row builder: shK[s][i] = Krev[i + 7 - s], via static funnel shift
template<int SH>
__device__ __forceinline__ void build_row(bf16_t* __restrict__ dst,
                                          const uint4* __restrict__ kb,
                                          int ln) {
#pragma unroll
    for (int r = 0; r < 3; ++r) {
        int c = ln + r * 64;                     // 192 chunks of 16B per row
        uint4 lo = kb[c];
        uint4 hi = kb[c + 1];
        unsigned int wd[8] = {lo.x, lo.y, lo.z, lo.w, hi.x, hi.y, hi.z, hi.w};
        uint4 o;
        constexpr int J = SH >> 2;
        if constexpr ((SH & 2) != 0) {
            o.x = (unsigned int)((((unsigned long long)wd[J+1] << 32) | wd[J+0]) >> 16);
            o.y = (unsigned int)((((unsigned long long)wd[J+2] << 32) | wd[J+1]) >> 16);
            o.z = (unsigned int)((((unsigned long long)wd[J+3] << 32) | wd[J+2]) >> 16);
            o.w = (unsigned int)((((unsigned long long)wd[J+4] << 32) | wd[J+3]) >> 16);
        } else {
            o.x = wd[J+0]; o.y = wd[J+1]; o.z = wd[J+2]; o.w = wd[J+3];
        }
        *(uint4*)(dst + c * 8) = o;
    }
}

// ---------------- causal conv (Toeplitz MFMA) + D*u + gelu -> gy bf16 -----
__global__ __launch_bounds__(512, 2) void k_conv(const bf16_t* __restrict__ ub,
                                                 const bf16_t* __restrict__ Krev,
                                                 const float* __restrict__ Dp,
                                                 bf16_t* __restrict__ gy) {
    int h = blockIdx.x;
    __shared__ __align__(16) bf16_t shK[8][1560];   // 24960 B
    __shared__ __align__(16) bf16_t ut[2][64][72];  // 18432 B
    int tid = threadIdx.x, lane = tid & 63, wv = tid >> 6;
    int q = lane >> 4, ln = lane & 15;

    const bf16_t* Kg = Krev + (size_t)h * 1536;
    {
        bf16_t* kb = &ut[0][0][0];
        if (tid < 192) *(uint4*)&kb[tid * 8] = *(const uint4*)&Kg[tid * 8];
        __syncthreads();
        const uint4* kb4 = (const uint4*)kb;
        bf16_t* dst = &shK[wv][0];
        switch (wv) {
            case 0: build_row<14>(dst, kb4, lane); break;
            case 1: build_row<12>(dst, kb4, lane); break;
            case 2: build_row<10>(dst, kb4, lane); break;
            case 3: build_row< 8>(dst, kb4, lane); break;
            case 4: build_row< 6>(dst, kb4, lane); break;
            case 5: build_row< 4>(dst, kb4, lane); break;
            case 6: build_row< 2>(dst, kb4, lane); break;
            default: build_row< 0>(dst, kb4, lane); break;
        }
        __syncthreads();
    }

    int sb = tid >> 3, sseg = tid & 7;
    const bf16_t* usrc = ub + ((size_t)sb * Hq + h) * Lq + sseg * 8;
    *(uint4*)&ut[0][sb][sseg * 8] = *(const uint4*)usrc;   // prologue t0=0

    f32x4 acc[8][4];
#pragma unroll
    for (int i = 0; i < 8; ++i)
#pragma unroll
        for (int j = 0; j < 4; ++j) acc[i][j] = (f32x4){0.f, 0.f, 0.f, 0.f};

    int Wl = wv << 7;
    float Dh = Dp[h];
    int cbase = 1279 - Wl + q * 8 - 7 - ((ln >> 3) << 3);
    const bf16_t* arow = &shK[ln & 7][0];
    __syncthreads();

#pragma unroll 2
    for (int step = 0; step < 16; ++step) {
        int t0 = step << 6;
        int cur = step & 1;
        uint4 pre;
        if (step < 15) pre = *(const uint4*)(usrc + t0 + 64);
        if (t0 < Wl + 128) {
            bf16x8 bfr[4][2];
#pragma unroll
            for (int nf = 0; nf < 4; ++nf)
#pragma unroll
                for (int kk = 0; kk < 2; ++kk)
                    bfr[nf][kk] = *(const bf16x8*)&ut[cur][nf * 16 + ln][kk * 32 + q * 8];
#pragma unroll
            for (int mf = 0; mf < 8; ++mf) {
#pragma unroll
                for (int kk = 0; kk < 2; ++kk) {
                    bf16x8 af = *(const bf16x8*)&arow[cbase + t0 + kk * 32 - mf * 16];
#pragma unroll
                    for (int nf = 0; nf < 4; ++nf)
                        acc[mf][nf] = __builtin_amdgcn_mfma_f32_16x16x32_bf16(
                            af, bfr[nf][kk], acc[mf][nf], 0, 0, 0);
                }
            }
            int ph = step - (wv << 1);
            if (ph == 0 || ph == 1) {
#pragma unroll
                for (int mh = 0; mh < 4; ++mh)
#pragma unroll
                    for (int nf = 0; nf < 4; ++nf) {
                        U2 uv;
                        uv.u = *(const uint2*)&ut[cur][nf * 16 + ln][mh * 16 + q * 4];
                        if (ph == 0) {
#pragma unroll
                            for (int rr = 0; rr < 4; ++rr)
                                acc[mh][nf][rr] += Dh * (float)uv.e[rr];
                        } else {
#pragma unroll
                            for (int rr = 0; rr < 4; ++rr)
                                acc[mh + 4][nf][rr] += Dh * (float)uv.e[rr];
                        }
                    }
            }
        }
        if (step < 15) *(uint4*)&ut[cur ^ 1][sb][sseg * 8] = pre;
        __syncthreads();
    }

#pragma unroll
    for (int mf = 0; mf < 8; ++mf) {
        int l = Wl + mf * 16 + q * 4;
#pragma unroll
        for (int nf = 0; nf < 4; ++nf) {
            int bb = nf * 16 + ln;
            size_t off = ((size_t)bb * Hq + h) * Lq + l;
            U2 ov;
#pragma unroll
            for (int rr = 0; rr < 4; ++rr) {
                float y = acc[mf][nf][rr];
                float t = 0.7978845608028654f * (y + 0.044715f * y * y * y);
                ov.e[rr] = (bf16_t)(0.5f * y * (1.f + tanhf(t)));
            }
            *(uint2*)&gy[off] = ov.u;
        }
    }
}

// ------- fused projA+projB v3: K-resident, depth-2 weight prefetch --------
// One block per (b, l-128-tile); 512 threads (8 waves); LDS tile 128x264.
// Weight fragments stream from L2 with a 2-deep register pipeline; the u
// tile loads issue at GEMM1's last k-step (T14); GEMM2's first weight
// fragments issue before GLU so its VALU work covers the L2 latency.
#define TBS 264
__global__ __launch_bounds__(512, 1) void k_projAB(const bf16_t* __restrict__ gyT,
                                                   const bf16_t* __restrict__ owb,
                                                   const float* __restrict__ ob,
                                                   const bf16_t* __restrict__ ubT,
                                                   const bf16_t* __restrict__ rsb,
                                                   const float* __restrict__ rb,
                                                   const float* __restrict__ sb,
                                                   const float* __restrict__ x,
                                                   float* __restrict__ out) {
    int bid = blockIdx.x;
    int b  = bid >> 3;
    int l0 = (bid & 7) << 7;
    __shared__ __align__(16) bf16_t TB[128 * TBS];   // 67584 B
    int tid = threadIdx.x, lane = tid & 63, wv = tid >> 6;
    int q = lane >> 4, ln = lane & 15;
    int lh = wv & 1, og = wv >> 1;        // l-half (64), o-group

    // ---- stage gy tile: TB[r][k] = gyT[b][l0+r][k]
    int sr = tid >> 2, sc = (tid & 3) * 8;          // 4 threads/row, 8 cols apart
    const bf16_t* usrc2 = ubT + ((size_t)b * Lq + l0 + sr) * 256 + sc;
    {
        const bf16_t* gsrc = gyT + ((size_t)b * Lq + l0 + sr) * 256 + sc;
        bf16_t* grow = &TB[sr * TBS + sc];
#pragma unroll
        for (int i = 0; i < 8; ++i)
            *(uint4*)(grow + i * 32) = *(const uint4*)(gsrc + i * 32);
    }

    // ---- GEMM1 weight bases + kk=0 prefetch (in flight across the barrier)
    const bf16_t* w0 = owb + ((size_t)og * 64 + ln) * 256 + q * 8;
    bf16x8 af[2][8];
#pragma unroll
    for (int mf = 0; mf < 8; ++mf)
        af[0][mf] = *(const bf16x8*)(w0 + (mf & 3) * 4096 + (mf >> 2) * 65536);
    __syncthreads();

    // ---- GEMM1: acc[mf][nf]; mf 0-3 = v1 rows og*64+mf*16, mf 4-7 = v2 (+256)
    f32x4 acc[8][4];
#pragma unroll
    for (int i = 0; i < 8; ++i)
#pragma unroll
        for (int j = 0; j < 4; ++j) acc[i][j] = (f32x4){0.f, 0.f, 0.f, 0.f};

    uint4 ureg[8];
#pragma unroll
    for (int kk = 0; kk < 8; ++kk) {
        const int cur = kk & 1, nxt = cur ^ 1;
        if (kk < 7) {
#pragma unroll
            for (int mf = 0; mf < 8; ++mf)
                af[nxt][mf] = *(const bf16x8*)(w0 + (mf & 3) * 4096 + (mf >> 2) * 65536
                                               + (kk + 1) * 32);
        } else {
            // T14: issue the u-tile loads here; HBM latency hides under the
            // final 32 MFMAs + the GLU phase.
#pragma unroll
            for (int i = 0; i < 8; ++i)
                ureg[i] = *(const uint4*)(usrc2 + i * 32);
        }
        bf16x8 bfr[4];
#pragma unroll
        for (int nf = 0; nf < 4; ++nf)
            bfr[nf] = *(const bf16x8*)&TB[(lh * 64 + nf * 16 + ln) * TBS + kk * 32 + q * 8];
#pragma unroll
        for (int mf = 0; mf < 8; ++mf)
#pragma unroll
            for (int nf = 0; nf < 4; ++nf)
                acc[mf][nf] = __builtin_amdgcn_mfma_f32_16x16x32_bf16(
                    af[cur][mf], bfr[nf], acc[mf][nf], 0, 0, 0);
    }

    // ---- GEMM2 weight base + kk=0 prefetch (covered by GLU's VALU work)
    const bf16_t* r0 = rsb + ((size_t)og * 128 + ln) * 256 + q * 8;
    bf16x8 rf[2][8];
#pragma unroll
    for (int nf = 0; nf < 8; ++nf)
        rf[0][nf] = *(const bf16x8*)(r0 + nf * 4096);

    __syncthreads();          // all TB(gy) reads done
    {   // write the prefetched u tile over TB
        bf16_t* urow = &TB[sr * TBS + sc];
#pragma unroll
        for (int i = 0; i < 8; ++i)
            *(uint4*)(urow + i * 32) = ureg[i];
    }
    __syncthreads();          // u visible

    // ---- GLU + u-add, in place: TB[row][c] = v1*sig(v2) + u
#pragma unroll
    for (int mf = 0; mf < 4; ++mf) {
        int c = og * 64 + mf * 16 + q * 4;
        F4 b1, b2;
        b1.v = *(const float4*)&ob[c];
        b2.v = *(const float4*)&ob[c + 256];
#pragma unroll
        for (int nf = 0; nf < 4; ++nf) {
            int row = lh * 64 + nf * 16 + ln;
            bf16_t* tp = &TB[row * TBS + c];
            U2 uv; uv.u = *(const uint2*)tp;
            U2 hv;
#pragma unroll
            for (int rr = 0; rr < 4; ++rr) {
                float v1 = acc[mf][nf][rr]     + b1.e[rr];
                float v2 = acc[mf + 4][nf][rr] + b2.e[rr];
                float sg = 1.f / (1.f + expf(-v2));
                hv.e[rr] = (bf16_t)(v1 * sg + (float)uv.e[rr]);
            }
            *(uint2*)tp = hv.u;
        }
    }
    __syncthreads();          // h2 visible

    // ---- GEMM2: acc2[mf l][nf o2]; A = h2 from LDS rows l, B = rsb rows o2
    f32x4 acc2[4][8];
#pragma unroll
    for (int i = 0; i < 4; ++i)
#pragma unroll
        for (int j = 0; j < 8; ++j) acc2[i][j] = (f32x4){0.f, 0.f, 0.f, 0.f};

#pragma unroll
    for (int kk = 0; kk < 8; ++kk) {
        const int cur = kk & 1, nxt = cur ^ 1;
        if (kk < 7) {
#pragma unroll
            for (int nf = 0; nf < 8; ++nf)
                rf[nxt][nf] = *(const bf16x8*)(r0 + nf * 4096 + (kk + 1) * 32);
        }
        bf16x8 afr[4];
#pragma unroll
        for (int mf = 0; mf < 4; ++mf)
            afr[mf] = *(const bf16x8*)&TB[(lh * 64 + mf * 16 + ln) * TBS + kk * 32 + q * 8];
#pragma unroll
        for (int nf = 0; nf < 8; ++nf)
#pragma unroll
            for (int mf = 0; mf < 4; ++mf)
                acc2[mf][nf] = __builtin_amdgcn_mfma_f32_16x16x32_bf16(
                    afr[mf], rf[cur][nf], acc2[mf][nf], 0, 0, 0);
    }

    // ---- epilogue: res (o2<256) += x, scale; skip (o2>=256) + sb
#pragma unroll
    for (int nf = 0; nf < 8; ++nf) {
        int o2 = og * 128 + nf * 16 + ln;
#pragma unroll
        for (int mf = 0; mf < 4; ++mf) {
            int l = l0 + lh * 64 + mf * 16 + q * 4;
            if (o2 < 256) {
                F4 xv; xv.v = *(const float4*)&x[((size_t)b * Hq + o2) * Lq + l];
                float rbv = rb[o2];
                F4 ov;
#pragma unroll
                for (int rr = 0; rr < 4; ++rr)
                    ov.e[rr] = (acc2[mf][nf][rr] + rbv + xv.e[rr]) * 0.70710678118654752f;
                *(float4*)&out[((size_t)b * Hq + o2) * Lq + l] = ov.v;
            } else {
                int c = o2 - 256;
                float sbv = sb[c];
                F4 ov;
#pragma unroll
                for (int rr = 0; rr < 4; ++rr)
                    ov.e[rr] = acc2[mf][nf][rr] + sbv;
                *(float4*)&out[(size_t)BHL + ((size_t)b * HSq + c) * Lq + l] = ov.v;
            }
        }
    }
}

extern "C" void kernel_launch(void* const* d_in, const int* in_sizes, int n_in,
                              void* d_out, int out_size, void* d_ws, size_t ws_size,
                              hipStream_t stream) {
    const float* x      = (const float*)d_in[0];
    const float* emb    = (const float*)d_in[1];
    const float* gnw    = (const float*)d_in[2];
    const float* gnb    = (const float*)d_in[3];
    const float* dpw    = (const float*)d_in[4];
    const float* dpb    = (const float*)d_in[5];
    const float* log_dt = (const float*)d_in[6];
    const float* Are    = (const float*)d_in[7];
    const float* Aim    = (const float*)d_in[8];
    const float* Cre    = (const float*)d_in[9];
    const float* Cim    = (const float*)d_in[10];
    const float* Dp     = (const float*)d_in[11];
    const float* ow     = (const float*)d_in[12];
    const float* ob     = (const float*)d_in[13];
    const float* rw     = (const float*)d_in[14];
    const float* rb     = (const float*)d_in[15];
    const float* sw     = (const float*)d_in[16];
    const float* sb     = (const float*)d_in[17];
    float* out = (float*)d_out;

    bf16_t* ub   = (bf16_t*)d_ws;                    // [B][H][L] bf16
    bf16_t* ubT  = ub   + (size_t)BHL;               // [B][L][H] bf16
    bf16_t* gy   = ubT  + (size_t)BHL;               // [B][H][L] bf16
    bf16_t* Krev = gy   + (size_t)BHL;               // [H][1536] bf16
    bf16_t* owb  = Krev + (size_t)256*1536;          // [512][256] bf16
    bf16_t* rsb  = owb  + (size_t)512*256;           // [512][256] bf16
    float*  dprj = (float*)(rsb + (size_t)512*256);  // [B][H]
    float*  stats = dprj + (size_t)Bq*Hq;            // [B*G][2]
    bf16_t* gyT = ub;    // reuse: ub dead after k_conv

    k_stats<<<Bq*Gq, 256, 0, stream>>>(x, stats);
    k_dproj<<<Bq*Hq/256, 256, 0, stream>>>(emb, dpw, dpb, dprj);
    k_unt<<<Bq*64, 256, 0, stream>>>(x, stats, gnw, gnb, dprj, ub, ubT);
    k_wcvt<<<512, 256, 0, stream>>>(ow, rw, sw, owb, rsb);
    k_kern<<<Hq, 256, 0, stream>>>(log_dt, Are, Aim, Cre, Cim, Krev);
    k_conv<<<Hq, 512, 0, stream>>>(ub, Krev, Dp, gy);
    k_tr<<<Bq*64, 256, 0, stream>>>(gy, gyT);
    k_projAB<<<Bq*8, 512, 0, stream>>>(gyT, owb, ob, ubT, rsb, rb, sb, x, out);
}